// Round 12
// baseline (185.971 us; speedup 1.0000x reference)
//
#include <hip/hip_runtime.h>

// Problem constants: B=4, L=2048, C=64, D=4
#define BB 4
#define LL 2048
#define CC 64
#define DD 4
#define AN (CC * DD)        // 256 A-entries per timestep per batch (c*4+i)
#define TPB 512             // threads per block (8 waves)
#define N4PB 4              // n4 values per block (quad -> full 64 B X lines)
#define NSEGS (TPB / N4PB)  // 128 time segments per half-chain
#define TT 8                // timesteps per thread
#define HALF (NSEGS * TT)   // 1024 timesteps covered per block
#define NBG (BB * (AN / N4PB))  // 256 (b, n4-group) pairs

typedef float f32x4 __attribute__((ext_vector_type(4)));

// ---------------------------------------------------------------------------
// One-dispatch pscan, v8: half-chain blocks + device-scope lookback.
// Measured constraints driving this design:
//  (1) Request-throughput-bound: eff. BW scales with bytes/request
//      (16B->1.4, 32B->1.65, 64B->2.2 TB/s measured v1/v7/v3). Quad lanes
//      on 4 consecutive n4 reading dwordx4 = full 64 B lines. Mandatory.
//  (2) Allocator never voluntarily holds X across the scan (v3=124 remat,
//      v7=76 remat, v4/v5 spill). Fix: TT=8 (X=64 VGPR, total ~115 < 128)
//      + asm "+v" pin after pass 1 -> remat impossible, budget sufficient.
//  (3) 1 block/CU serializes scan barriers (v3, 50 us). Half-chain blocks
//      -> 512 blocks = 2/CU, 16 waves/CU; cross-half carry via lookback:
//      h=0 publishes its s-total (32 B/chain-group), h=1 spin-waits.
//      Deadlock-free: launch_bounds(512,4) caps VGPR at 128 and LDS is
//      22.7 KB -> ALL 512 blocks co-resident by capacity.
// Traffic: read A+X once (80 MB) + write out once (64 MB) + 33 KB handshake.
// ---------------------------------------------------------------------------
__global__ __launch_bounds__(TPB, 4) void pscan_lookback(
    const float* __restrict__ A_re, const float* __restrict__ A_im,
    const f32x4* __restrict__ X_re4, const f32x4* __restrict__ X_im4,
    float* __restrict__ ws_data, unsigned int* __restrict__ flags,
    f32x4* __restrict__ out4) {
  // Swizzle (bijective on [0,512)): XCD k hosts bg in [32k,32k+32), BOTH
  // halves -> producer/consumer pairs share an L2 (fast handshake) and
  // adjacent n4g (sharing 64 B A-lines) are co-located.
  const int xcd = blockIdx.x & 7;
  const int idx = blockIdx.x >> 3;           // [0,64)
  const int h   = idx >> 5;                  // 0 = first half, 1 = second
  const int bg  = xcd * 32 + (idx & 31);     // [0,256)
  const int b   = bg >> 6;                   // [0,4)
  const int n4g = bg & 63;                   // [0,64)
  const int tid  = threadIdx.x;
  const int n4l  = tid & (N4PB - 1);
  const int tseg = tid >> 2;                 // [0,128)
  const int n4   = n4g * N4PB + n4l;
  const int tg0  = h * HALF + tseg * TT;     // global start timestep
  const int base = (b * LL + tg0) * AN + n4; // index for A (float), X (f32x4)

  // ---- pass 1: stream A,X (full-line quads); segment aggregate ----
  float ar[TT], ai[TT];
  float xre[TT][4], xim[TT][4];
  float p_re = 1.f, p_im = 0.f;
  float s_re[4] = {0.f, 0.f, 0.f, 0.f};
  float s_im[4] = {0.f, 0.f, 0.f, 0.f};
#pragma unroll
  for (int t = 0; t < TT; ++t) {
    const float are = A_re[base + t * AN];
    const float aim = A_im[base + t * AN];
    ar[t] = are; ai[t] = aim;
    const f32x4 tr = X_re4[base + t * AN];
    const f32x4 ti = X_im4[base + t * AN];
#pragma unroll
    for (int j = 0; j < 4; ++j) { xre[t][j] = tr[j]; xim[t][j] = ti[j]; }
    const float npre = are * p_re - aim * p_im;
    const float npim = are * p_im + aim * p_re;
    p_re = npre; p_im = npim;
#pragma unroll
    for (int j = 0; j < 4; ++j) {
      const float nsre = are * s_re[j] - aim * s_im[j] + xre[t][j];
      const float nsim = are * s_im[j] + aim * s_re[j] + xim[t][j];
      s_re[j] = nsre; s_im[j] = nsim;
    }
  }
  // Pin A,X in VGPRs: as asm outputs they can no longer be rematerialized
  // from memory, and ~115 live VGPR fits the 128-VGPR tier -> no spill.
#pragma unroll
  for (int t = 0; t < TT; ++t) {
    asm volatile("" : "+v"(ar[t]), "+v"(ai[t]),
                      "+v"(xre[t][0]), "+v"(xre[t][1]),
                      "+v"(xre[t][2]), "+v"(xre[t][3]),
                      "+v"(xim[t][0]), "+v"(xim[t][1]),
                      "+v"(xim[t][2]), "+v"(xim[t][3]));
  }

  // ---- block-level inclusive Hillis-Steele scan (per n4l chain) ----
  // 11-float tuple stride (coprime 32): worst aliasing 2-way = free.
  __shared__ float lds[TPB * 11];
  __shared__ float eLDS[32];
  const int q = tid * 11;
  lds[q + 0] = p_re; lds[q + 1] = p_im;
#pragma unroll
  for (int j = 0; j < 4; ++j) { lds[q + 2 + j] = s_re[j]; lds[q + 6 + j] = s_im[j]; }

  float vp_re = p_re, vp_im = p_im;
  float vs_re[4], vs_im[4];
#pragma unroll
  for (int j = 0; j < 4; ++j) { vs_re[j] = s_re[j]; vs_im[j] = s_im[j]; }

  for (int d = 1; d < NSEGS; d <<= 1) {      // 7 rounds
    __syncthreads();
    float wp_re = 1.f, wp_im = 0.f;
    float ws_re[4] = {0.f, 0.f, 0.f, 0.f};
    float ws_im[4] = {0.f, 0.f, 0.f, 0.f};
    if (tseg >= d) {
      const int q2 = q - d * (N4PB * 11);
      wp_re = lds[q2 + 0]; wp_im = lds[q2 + 1];
#pragma unroll
      for (int j = 0; j < 4; ++j) { ws_re[j] = lds[q2 + 2 + j]; ws_im[j] = lds[q2 + 6 + j]; }
    }
    __syncthreads();
    if (tseg >= d) {
      const float np_re = vp_re * wp_re - vp_im * wp_im;
      const float np_im = vp_re * wp_im + vp_im * wp_re;
#pragma unroll
      for (int j = 0; j < 4; ++j) {
        const float ns_re = vp_re * ws_re[j] - vp_im * ws_im[j] + vs_re[j];
        const float ns_im = vp_re * ws_im[j] + vp_im * ws_re[j] + vs_im[j];
        vs_re[j] = ns_re; vs_im[j] = ns_im;
      }
      vp_re = np_re; vp_im = np_im;
      lds[q + 0] = vp_re; lds[q + 1] = vp_im;
#pragma unroll
      for (int j = 0; j < 4; ++j) { lds[q + 2 + j] = vs_re[j]; lds[q + 6 + j] = vs_im[j]; }
    }
  }
  __syncthreads();

  // ---- h=0 publishes its inclusive s-total (the y at t=HALF-1) ----
  if (h == 0 && tseg == NSEGS - 1) {
    float* wd = ws_data + bg * 32 + n4l * 8;
#pragma unroll
    for (int j = 0; j < 4; ++j) { wd[j * 2] = vs_re[j]; wd[j * 2 + 1] = vs_im[j]; }
    // release: my 8 stores above are visible to whoever acquires this flag
    __hip_atomic_fetch_add(&flags[bg], 1u, __ATOMIC_RELEASE, __HIP_MEMORY_SCOPE_AGENT);
  }

  // ---- exclusive within-block tuple (lp, ls) ----
  float lp_re = 1.f, lp_im = 0.f;
  float ls_re[4] = {0.f, 0.f, 0.f, 0.f};
  float ls_im[4] = {0.f, 0.f, 0.f, 0.f};
  if (tseg > 0) {
    const int qc = q - N4PB * 11;
    lp_re = lds[qc + 0]; lp_im = lds[qc + 1];
#pragma unroll
    for (int j = 0; j < 4; ++j) { ls_re[j] = lds[qc + 2 + j]; ls_im[j] = lds[qc + 6 + j]; }
  }

  // ---- h=1 acquires the external carry E from its h=0 partner ----
  float e_re[4] = {0.f, 0.f, 0.f, 0.f};
  float e_im[4] = {0.f, 0.f, 0.f, 0.f};
  if (h == 1) {
    if (tid < 32) {
      while (__hip_atomic_load(&flags[bg], __ATOMIC_ACQUIRE, __HIP_MEMORY_SCOPE_AGENT) < 4u) {
        __builtin_amdgcn_s_sleep(1);
      }
      eLDS[tid] = ws_data[bg * 32 + tid];   // post-acquire: coherent
    }
    __syncthreads();
#pragma unroll
    for (int j = 0; j < 4; ++j) {
      e_re[j] = eLDS[n4l * 8 + j * 2];
      e_im[j] = eLDS[n4l * 8 + j * 2 + 1];
    }
  }

  // ---- seed: y = ls + lp*E (E=0 for h=0) ----
  float y_re[4], y_im[4];
#pragma unroll
  for (int j = 0; j < 4; ++j) {
    y_re[j] = ls_re[j] + lp_re * e_re[j] - lp_im * e_im[j];
    y_im[j] = ls_im[j] + lp_re * e_im[j] + lp_im * e_re[j];
  }

  // ---- pass 2: recurrence from pinned registers, coalesced stores ----
  const int ob = (b * LL + tg0) * (2 * AN) + n4 * 2;  // f32x4 index into out
#pragma unroll
  for (int t = 0; t < TT; ++t) {
    const float are = ar[t], aim = ai[t];
#pragma unroll
    for (int j = 0; j < 4; ++j) {
      const float ny_re = are * y_re[j] - aim * y_im[j] + xre[t][j];
      const float ny_im = are * y_im[j] + aim * y_re[j] + xim[t][j];
      y_re[j] = ny_re; y_im[j] = ny_im;
    }
    f32x4 o0 = {y_re[0], y_im[0], y_re[1], y_im[1]};
    f32x4 o1 = {y_re[2], y_im[2], y_re[3], y_im[3]};
    out4[ob + t * (2 * AN)]     = o0;
    out4[ob + t * (2 * AN) + 1] = o1;
  }
}

extern "C" void kernel_launch(void* const* d_in, const int* in_sizes, int n_in,
                              void* d_out, int out_size, void* d_ws, size_t ws_size,
                              hipStream_t stream) {
  const float* A_re  = (const float*)d_in[0];
  const float* A_im  = (const float*)d_in[1];
  const f32x4* X_re4 = (const f32x4*)d_in[2];
  const f32x4* X_im4 = (const f32x4*)d_in[3];
  f32x4* out4 = (f32x4*)d_out;

  // workspace: 32 KB carry data, then 1 KB flags (zeroed every launch)
  float* ws_data = (float*)d_ws;
  unsigned int* flags = (unsigned int*)((char*)d_ws + NBG * 32 * sizeof(float));
  hipMemsetAsync(flags, 0, NBG * sizeof(unsigned int), stream);

  const int blocks = 2 * NBG;   // 512: one per (half, b, n4-group)
  pscan_lookback<<<blocks, TPB, 0, stream>>>(A_re, A_im, X_re4, X_im4,
                                             ws_data, flags, out4);
}

// Round 13
// 175.972 us; speedup vs baseline: 1.0568x; 1.0568x over previous
//
#include <hip/hip_runtime.h>

// Problem constants: B=4, L=2048, C=64, D=4
#define BB 4
#define LL 2048
#define CC 64
#define DD 4
#define AN (CC * DD)        // 256 A-entries per timestep per batch (c*4+i)
#define TPB 512             // threads per block (8 waves)
#define N4PB 4              // n4 values per block (quad -> full 64 B X lines)
#define NSEGS (TPB / N4PB)  // 128 time segments per half-chain
#define TT 8                // timesteps per thread
#define HALF (NSEGS * TT)   // 1024 timesteps covered per block
#define NBG (BB * (AN / N4PB))  // 256 (b, n4-group) pairs

typedef float f32x4 __attribute__((ext_vector_type(4)));

// ---------------------------------------------------------------------------
// One-dispatch pscan, v9 = v8 minus the failed register-pinning.
// Measured design rules (rounds 5-12):
//  (1) Full 64 B lines per quad or BW collapses (16B->1.4, 32B->1.65,
//      64B->2.2+ TB/s). N4PB=4 mandatory.
//  (2) The allocator WILL NOT hold X across the scan: launch_bounds hints,
//      waves_per_eu(4,4), and asm-pin all produced 64-VGPR + spill/remat.
//      So don't fight it: pass 2 re-READS X; re-reads hit L2/LLC (v3
//      measured FETCH=41 MB with this exact behavior). A (16 VGPR) is kept.
//  (3) 1 block/CU serializes scan barriers (v3: 50 us, Occ 19%). Half-chain
//      blocks -> 512 blocks = 2/CU = 16 waves/CU; cross-half carry via the
//      v8-verified lookback: h=0 publishes its s-total, h=1 spin-waits.
//      Deadlock-free by capacity: launch_bounds(512,4) caps VGPR at 128 and
//      LDS is 22.7 KB -> all 512 blocks co-resident.
// Traffic: A+X once (80 MB, partly LLC-served) + out once (64 MB) + 33 KB.
// ---------------------------------------------------------------------------
__global__ __launch_bounds__(TPB, 4) void pscan_lookback2(
    const float* __restrict__ A_re, const float* __restrict__ A_im,
    const f32x4* __restrict__ X_re4, const f32x4* __restrict__ X_im4,
    float* __restrict__ ws_data, unsigned int* __restrict__ flags,
    f32x4* __restrict__ out4) {
  // Swizzle (bijective on [0,512)): XCD k hosts bg in [32k,32k+32), BOTH
  // halves -> producer/consumer pairs share an L2 (fast handshake), and
  // adjacent n4g (sharing 64 B A-lines) are co-located.
  const int xcd = blockIdx.x & 7;
  const int idx = blockIdx.x >> 3;           // [0,64)
  const int h   = idx >> 5;                  // 0 = first half, 1 = second
  const int bg  = xcd * 32 + (idx & 31);     // [0,256)
  const int b   = bg >> 6;                   // [0,4)
  const int n4g = bg & 63;                   // [0,64)
  const int tid  = threadIdx.x;
  const int n4l  = tid & (N4PB - 1);
  const int tseg = tid >> 2;                 // [0,128)
  const int n4   = n4g * N4PB + n4l;
  const int tg0  = h * HALF + tseg * TT;     // global start timestep
  const int base = (b * LL + tg0) * AN + n4; // index for A (float), X (f32x4)

  // ---- pass 1: stream A,X (full-line quads); segment aggregate ----
  // A kept in registers (16 VGPR); X deliberately NOT kept (see rule 2).
  float ar[TT], ai[TT];
  float p_re = 1.f, p_im = 0.f;
  float s_re[4] = {0.f, 0.f, 0.f, 0.f};
  float s_im[4] = {0.f, 0.f, 0.f, 0.f};
#pragma unroll
  for (int t = 0; t < TT; ++t) {
    const float are = A_re[base + t * AN];
    const float aim = A_im[base + t * AN];
    ar[t] = are; ai[t] = aim;
    const f32x4 xr = X_re4[base + t * AN];
    const f32x4 xi = X_im4[base + t * AN];
    const float npre = are * p_re - aim * p_im;
    const float npim = are * p_im + aim * p_re;
    p_re = npre; p_im = npim;
#pragma unroll
    for (int j = 0; j < 4; ++j) {
      const float nsre = are * s_re[j] - aim * s_im[j] + xr[j];
      const float nsim = are * s_im[j] + aim * s_re[j] + xi[j];
      s_re[j] = nsre; s_im[j] = nsim;
    }
  }

  // ---- block-level inclusive Hillis-Steele scan (per n4l chain) ----
  // 11-float tuple stride (coprime 32): worst aliasing 2-way = free.
  __shared__ float lds[TPB * 11];
  __shared__ float eLDS[32];
  const int q = tid * 11;
  lds[q + 0] = p_re; lds[q + 1] = p_im;
#pragma unroll
  for (int j = 0; j < 4; ++j) { lds[q + 2 + j] = s_re[j]; lds[q + 6 + j] = s_im[j]; }

  float vp_re = p_re, vp_im = p_im;
  float vs_re[4], vs_im[4];
#pragma unroll
  for (int j = 0; j < 4; ++j) { vs_re[j] = s_re[j]; vs_im[j] = s_im[j]; }

  for (int d = 1; d < NSEGS; d <<= 1) {      // 7 rounds
    __syncthreads();
    float wp_re = 1.f, wp_im = 0.f;
    float ws_re[4] = {0.f, 0.f, 0.f, 0.f};
    float ws_im[4] = {0.f, 0.f, 0.f, 0.f};
    if (tseg >= d) {
      const int q2 = q - d * (N4PB * 11);
      wp_re = lds[q2 + 0]; wp_im = lds[q2 + 1];
#pragma unroll
      for (int j = 0; j < 4; ++j) { ws_re[j] = lds[q2 + 2 + j]; ws_im[j] = lds[q2 + 6 + j]; }
    }
    __syncthreads();
    if (tseg >= d) {
      const float np_re = vp_re * wp_re - vp_im * wp_im;
      const float np_im = vp_re * wp_im + vp_im * wp_re;
#pragma unroll
      for (int j = 0; j < 4; ++j) {
        const float ns_re = vp_re * ws_re[j] - vp_im * ws_im[j] + vs_re[j];
        const float ns_im = vp_re * ws_im[j] + vp_im * ws_re[j] + vs_im[j];
        vs_re[j] = ns_re; vs_im[j] = ns_im;
      }
      vp_re = np_re; vp_im = np_im;
      lds[q + 0] = vp_re; lds[q + 1] = vp_im;
#pragma unroll
      for (int j = 0; j < 4; ++j) { lds[q + 2 + j] = vs_re[j]; lds[q + 6 + j] = vs_im[j]; }
    }
  }
  __syncthreads();

  // ---- h=0 publishes its inclusive s-total (the y at t=HALF-1) ----
  if (h == 0 && tseg == NSEGS - 1) {
    float* wd = ws_data + bg * 32 + n4l * 8;
#pragma unroll
    for (int j = 0; j < 4; ++j) { wd[j * 2] = vs_re[j]; wd[j * 2 + 1] = vs_im[j]; }
    // release: the 8 stores above are visible to whoever acquires this flag
    __hip_atomic_fetch_add(&flags[bg], 1u, __ATOMIC_RELEASE, __HIP_MEMORY_SCOPE_AGENT);
  }

  // ---- exclusive within-block tuple (lp, ls) ----
  float lp_re = 1.f, lp_im = 0.f;
  float ls_re[4] = {0.f, 0.f, 0.f, 0.f};
  float ls_im[4] = {0.f, 0.f, 0.f, 0.f};
  if (tseg > 0) {
    const int qc = q - N4PB * 11;
    lp_re = lds[qc + 0]; lp_im = lds[qc + 1];
#pragma unroll
    for (int j = 0; j < 4; ++j) { ls_re[j] = lds[qc + 2 + j]; ls_im[j] = lds[qc + 6 + j]; }
  }

  // ---- h=1 acquires the external carry E from its h=0 partner ----
  float e_re[4] = {0.f, 0.f, 0.f, 0.f};
  float e_im[4] = {0.f, 0.f, 0.f, 0.f};
  if (h == 1) {
    if (tid < 32) {
      while (__hip_atomic_load(&flags[bg], __ATOMIC_ACQUIRE, __HIP_MEMORY_SCOPE_AGENT) < 4u) {
        __builtin_amdgcn_s_sleep(1);
      }
      eLDS[tid] = ws_data[bg * 32 + tid];   // post-acquire: coherent
    }
    __syncthreads();
#pragma unroll
    for (int j = 0; j < 4; ++j) {
      e_re[j] = eLDS[n4l * 8 + j * 2];
      e_im[j] = eLDS[n4l * 8 + j * 2 + 1];
    }
  }

  // ---- seed: y = ls + lp*E (E=0 for h=0) ----
  float y_re[4], y_im[4];
#pragma unroll
  for (int j = 0; j < 4; ++j) {
    y_re[j] = ls_re[j] + lp_re * e_re[j] - lp_im * e_im[j];
    y_im[j] = ls_im[j] + lp_re * e_im[j] + lp_im * e_re[j];
  }

  // ---- pass 2: re-read X (L2/LLC-warm, full-line quads), apply, store ----
  const int ob = (b * LL + tg0) * (2 * AN) + n4 * 2;  // f32x4 index into out
#pragma unroll
  for (int t = 0; t < TT; ++t) {
    const float are = ar[t], aim = ai[t];
    const f32x4 xr = X_re4[base + t * AN];
    const f32x4 xi = X_im4[base + t * AN];
#pragma unroll
    for (int j = 0; j < 4; ++j) {
      const float ny_re = are * y_re[j] - aim * y_im[j] + xr[j];
      const float ny_im = are * y_im[j] + aim * y_re[j] + xi[j];
      y_re[j] = ny_re; y_im[j] = ny_im;
    }
    f32x4 o0 = {y_re[0], y_im[0], y_re[1], y_im[1]};
    f32x4 o1 = {y_re[2], y_im[2], y_re[3], y_im[3]};
    out4[ob + t * (2 * AN)]     = o0;
    out4[ob + t * (2 * AN) + 1] = o1;
  }
}

extern "C" void kernel_launch(void* const* d_in, const int* in_sizes, int n_in,
                              void* d_out, int out_size, void* d_ws, size_t ws_size,
                              hipStream_t stream) {
  const float* A_re  = (const float*)d_in[0];
  const float* A_im  = (const float*)d_in[1];
  const f32x4* X_re4 = (const f32x4*)d_in[2];
  const f32x4* X_im4 = (const f32x4*)d_in[3];
  f32x4* out4 = (f32x4*)d_out;

  // workspace: 32 KB carry data, then 1 KB flags (zeroed every launch)
  float* ws_data = (float*)d_ws;
  unsigned int* flags = (unsigned int*)((char*)d_ws + NBG * 32 * sizeof(float));
  hipMemsetAsync(flags, 0, NBG * sizeof(unsigned int), stream);

  const int blocks = 2 * NBG;   // 512: one per (half, b, n4-group)
  pscan_lookback2<<<blocks, TPB, 0, stream>>>(A_re, A_im, X_re4, X_im4,
                                              ws_data, flags, out4);
}

// Round 14
// 146.242 us; speedup vs baseline: 1.2717x; 1.2033x over previous
//
#include <hip/hip_runtime.h>

// Problem constants: B=4, L=2048, C=64, D=4
#define BB 4
#define LL 2048
#define CC 64
#define DD 4
#define AN (CC * DD)        // 256 A-entries per timestep per batch (c*4+i)
#define TPB 512             // threads per block (8 waves)
#define N4PB 4              // n4 values per block (quad -> full 64 B X lines)
#define NSEGS (TPB / N4PB)  // 128 time segments per chain
#define TT (LL / NSEGS)     // 16 timesteps per thread
#define TH (TT / 2)         // 8 timesteps stashed in LDS
#define SCAN_FLOATS (TPB * 11)
#define SHMEM_BYTES (SCAN_FLOATS * 4 + 2 * TH * TPB * 16)  // 22528+131072=153600

typedef float f32x4 __attribute__((ext_vector_type(4)));

// ---------------------------------------------------------------------------
// v10 = v3 (best: 50 us) + LDS X-stash for the first half of each thread's
// timesteps. Rationale from v3's counters: HBM-level only 2.2 TB/s BUT
// fabric-level ~228 MB in 50 us = 4.6 TB/s (pass-2 remat re-reads X from
// LLC). More waves lost twice (v7/v13); removing fabric bytes is the lever.
// LDS 160 KB/CU: scan buffer 22.5 KB + half-X stash 128 KB = 150.5 KB fits.
// Pass 2: t=0..7 from LDS while t=8..15 LLC loads (issued first) fly.
// Requires dynamic shared 153.6 KB (hipFuncSetAttribute, one-time);
// falls back to v3-verbatim if the attribute is rejected.
// ---------------------------------------------------------------------------
__global__ __launch_bounds__(TPB, 2) void pscan_v10(
    const float* __restrict__ A_re, const float* __restrict__ A_im,
    const f32x4* __restrict__ X_re4, const f32x4* __restrict__ X_im4,
    f32x4* __restrict__ out4) {
  extern __shared__ char smem[];
  float* lds  = (float*)smem;                          // scan tuples
  f32x4* stR  = (f32x4*)(smem + SCAN_FLOATS * 4);      // X_re stash [TH][TPB]
  f32x4* stI  = stR + TH * TPB;                        // X_im stash [TH][TPB]

  const int sid = (blockIdx.x & 7) * 32 + (blockIdx.x >> 3);  // XCD swizzle
  const int b    = sid >> 6;
  const int n4g  = sid & 63;
  const int tid  = threadIdx.x;
  const int n4l  = tid & (N4PB - 1);
  const int tseg = tid >> 2;                 // [0,128)
  const int n4   = n4g * N4PB + n4l;
  const int t0   = tseg * TT;
  const int base = (b * LL + t0) * AN + n4;  // index for A (float), X (f32x4)

  // ---- pass 1: stream A,X (full-line quads); stash t<TH X in LDS ----
  float ar[TT], ai[TT];
  float p_re = 1.f, p_im = 0.f;
  float s_re[4] = {0.f, 0.f, 0.f, 0.f};
  float s_im[4] = {0.f, 0.f, 0.f, 0.f};
#pragma unroll
  for (int t = 0; t < TT; ++t) {
    const float are = A_re[base + t * AN];
    const float aim = A_im[base + t * AN];
    ar[t] = are; ai[t] = aim;
    const f32x4 xr = X_re4[base + t * AN];
    const f32x4 xi = X_im4[base + t * AN];
    if (t < TH) { stR[t * TPB + tid] = xr; stI[t * TPB + tid] = xi; }
    const float npre = are * p_re - aim * p_im;
    const float npim = are * p_im + aim * p_re;
    p_re = npre; p_im = npim;
#pragma unroll
    for (int j = 0; j < 4; ++j) {
      const float nsre = are * s_re[j] - aim * s_im[j] + xr[j];
      const float nsim = are * s_im[j] + aim * s_re[j] + xi[j];
      s_re[j] = nsre; s_im[j] = nsim;
    }
  }

  // ---- block-level inclusive Hillis-Steele scan (per n4l chain) ----
  const int q = tid * 11;
  lds[q + 0] = p_re; lds[q + 1] = p_im;
#pragma unroll
  for (int j = 0; j < 4; ++j) { lds[q + 2 + j] = s_re[j]; lds[q + 6 + j] = s_im[j]; }

  float vp_re = p_re, vp_im = p_im;
  float vs_re[4], vs_im[4];
#pragma unroll
  for (int j = 0; j < 4; ++j) { vs_re[j] = s_re[j]; vs_im[j] = s_im[j]; }

  for (int d = 1; d < NSEGS; d <<= 1) {      // 7 rounds
    __syncthreads();
    float wp_re = 1.f, wp_im = 0.f;
    float ws_re[4] = {0.f, 0.f, 0.f, 0.f};
    float ws_im[4] = {0.f, 0.f, 0.f, 0.f};
    if (tseg >= d) {
      const int q2 = q - d * (N4PB * 11);
      wp_re = lds[q2 + 0]; wp_im = lds[q2 + 1];
#pragma unroll
      for (int j = 0; j < 4; ++j) { ws_re[j] = lds[q2 + 2 + j]; ws_im[j] = lds[q2 + 6 + j]; }
    }
    __syncthreads();
    if (tseg >= d) {
      const float np_re = vp_re * wp_re - vp_im * wp_im;
      const float np_im = vp_re * wp_im + vp_im * wp_re;
#pragma unroll
      for (int j = 0; j < 4; ++j) {
        const float ns_re = vp_re * ws_re[j] - vp_im * ws_im[j] + vs_re[j];
        const float ns_im = vp_re * ws_im[j] + vp_im * ws_re[j] + vs_im[j];
        vs_re[j] = ns_re; vs_im[j] = ns_im;
      }
      vp_re = np_re; vp_im = np_im;
      lds[q + 0] = vp_re; lds[q + 1] = vp_im;
#pragma unroll
      for (int j = 0; j < 4; ++j) { lds[q + 2 + j] = vs_re[j]; lds[q + 6 + j] = vs_im[j]; }
    }
  }
  __syncthreads();

  // ---- exclusive carry = inclusive tuple of tseg-1 (same n4l) ----
  float y_re[4] = {0.f, 0.f, 0.f, 0.f};
  float y_im[4] = {0.f, 0.f, 0.f, 0.f};
  if (tseg > 0) {
    const int qc = q - N4PB * 11;
#pragma unroll
    for (int j = 0; j < 4; ++j) { y_re[j] = lds[qc + 2 + j]; y_im[j] = lds[qc + 6 + j]; }
  }

  // ---- pass 2: issue LLC re-loads for t>=TH first (latency hides under
  //      the LDS half), then run the recurrence t=0..15 and store ----
  f32x4 xr2[TT - TH], xi2[TT - TH];
#pragma unroll
  for (int t = TH; t < TT; ++t) {
    xr2[t - TH] = X_re4[base + t * AN];
    xi2[t - TH] = X_im4[base + t * AN];
  }

  const int ob = (b * LL + t0) * (2 * AN) + n4 * 2;  // f32x4 index into out
#pragma unroll
  for (int t = 0; t < TH; ++t) {
    const f32x4 xr = stR[t * TPB + tid];
    const f32x4 xi = stI[t * TPB + tid];
    const float are = ar[t], aim = ai[t];
#pragma unroll
    for (int j = 0; j < 4; ++j) {
      const float ny_re = are * y_re[j] - aim * y_im[j] + xr[j];
      const float ny_im = are * y_im[j] + aim * y_re[j] + xi[j];
      y_re[j] = ny_re; y_im[j] = ny_im;
    }
    f32x4 o0 = {y_re[0], y_im[0], y_re[1], y_im[1]};
    f32x4 o1 = {y_re[2], y_im[2], y_re[3], y_im[3]};
    out4[ob + t * (2 * AN)]     = o0;
    out4[ob + t * (2 * AN) + 1] = o1;
  }
#pragma unroll
  for (int t = TH; t < TT; ++t) {
    const f32x4 xr = xr2[t - TH];
    const f32x4 xi = xi2[t - TH];
    const float are = ar[t], aim = ai[t];
#pragma unroll
    for (int j = 0; j < 4; ++j) {
      const float ny_re = are * y_re[j] - aim * y_im[j] + xr[j];
      const float ny_im = are * y_im[j] + aim * y_re[j] + xi[j];
      y_re[j] = ny_re; y_im[j] = ny_im;
    }
    f32x4 o0 = {y_re[0], y_im[0], y_re[1], y_im[1]};
    f32x4 o1 = {y_re[2], y_im[2], y_re[3], y_im[3]};
    out4[ob + t * (2 * AN)]     = o0;
    out4[ob + t * (2 * AN) + 1] = o1;
  }
}

// ---------------------------------------------------------------------------
// Fallback: round-7 kernel verbatim (measured 50 us) in case the dynamic-LDS
// attribute is rejected.
// ---------------------------------------------------------------------------
__global__ __launch_bounds__(TPB, 2) void pscan_onepass3(
    const float* __restrict__ A_re, const float* __restrict__ A_im,
    const f32x4* __restrict__ X_re4, const f32x4* __restrict__ X_im4,
    f32x4* __restrict__ out4) {
  const int sid = (blockIdx.x & 7) * 32 + (blockIdx.x >> 3);
  const int b    = sid >> 6;
  const int n4g  = sid & 63;
  const int tid  = threadIdx.x;
  const int n4l  = tid & (N4PB - 1);
  const int tseg = tid >> 2;
  const int n4   = n4g * N4PB + n4l;
  const int t0   = tseg * TT;
  const int base = (b * LL + t0) * AN + n4;

  float ar[TT], ai[TT];
  f32x4 xr[TT], xi[TT];
  float p_re = 1.f, p_im = 0.f;
  float s_re[4] = {0.f, 0.f, 0.f, 0.f};
  float s_im[4] = {0.f, 0.f, 0.f, 0.f};
#pragma unroll
  for (int t = 0; t < TT; ++t) {
    const float are = A_re[base + t * AN];
    const float aim = A_im[base + t * AN];
    ar[t] = are; ai[t] = aim;
    xr[t] = X_re4[base + t * AN];
    xi[t] = X_im4[base + t * AN];
    const float npre = are * p_re - aim * p_im;
    const float npim = are * p_im + aim * p_re;
    p_re = npre; p_im = npim;
#pragma unroll
    for (int j = 0; j < 4; ++j) {
      const float nsre = are * s_re[j] - aim * s_im[j] + xr[t][j];
      const float nsim = are * s_im[j] + aim * s_re[j] + xi[t][j];
      s_re[j] = nsre; s_im[j] = nsim;
    }
  }

  __shared__ float lds[TPB * 11];
  const int q = tid * 11;
  lds[q + 0] = p_re; lds[q + 1] = p_im;
#pragma unroll
  for (int j = 0; j < 4; ++j) { lds[q + 2 + j] = s_re[j]; lds[q + 6 + j] = s_im[j]; }

  float vp_re = p_re, vp_im = p_im;
  float vs_re[4], vs_im[4];
#pragma unroll
  for (int j = 0; j < 4; ++j) { vs_re[j] = s_re[j]; vs_im[j] = s_im[j]; }

  for (int d = 1; d < NSEGS; d <<= 1) {
    __syncthreads();
    float wp_re = 1.f, wp_im = 0.f;
    float ws_re[4] = {0.f, 0.f, 0.f, 0.f};
    float ws_im[4] = {0.f, 0.f, 0.f, 0.f};
    if (tseg >= d) {
      const int q2 = q - d * (N4PB * 11);
      wp_re = lds[q2 + 0]; wp_im = lds[q2 + 1];
#pragma unroll
      for (int j = 0; j < 4; ++j) { ws_re[j] = lds[q2 + 2 + j]; ws_im[j] = lds[q2 + 6 + j]; }
    }
    __syncthreads();
    if (tseg >= d) {
      const float np_re = vp_re * wp_re - vp_im * wp_im;
      const float np_im = vp_re * wp_im + vp_im * wp_re;
#pragma unroll
      for (int j = 0; j < 4; ++j) {
        const float ns_re = vp_re * ws_re[j] - vp_im * ws_im[j] + vs_re[j];
        const float ns_im = vp_re * ws_im[j] + vp_im * ws_re[j] + vs_im[j];
        vs_re[j] = ns_re; vs_im[j] = ns_im;
      }
      vp_re = np_re; vp_im = np_im;
      lds[q + 0] = vp_re; lds[q + 1] = vp_im;
#pragma unroll
      for (int j = 0; j < 4; ++j) { lds[q + 2 + j] = vs_re[j]; lds[q + 6 + j] = vs_im[j]; }
    }
  }
  __syncthreads();

  float y_re[4] = {0.f, 0.f, 0.f, 0.f};
  float y_im[4] = {0.f, 0.f, 0.f, 0.f};
  if (tseg > 0) {
    const int qc = q - N4PB * 11;
#pragma unroll
    for (int j = 0; j < 4; ++j) { y_re[j] = lds[qc + 2 + j]; y_im[j] = lds[qc + 6 + j]; }
  }

  const int ob = (b * LL + t0) * (2 * AN) + n4 * 2;
#pragma unroll
  for (int t = 0; t < TT; ++t) {
    const float are = ar[t], aim = ai[t];
#pragma unroll
    for (int j = 0; j < 4; ++j) {
      const float ny_re = are * y_re[j] - aim * y_im[j] + xr[t][j];
      const float ny_im = are * y_im[j] + aim * y_re[j] + xi[t][j];
      y_re[j] = ny_re; y_im[j] = ny_im;
    }
    f32x4 o0 = {y_re[0], y_im[0], y_re[1], y_im[1]};
    f32x4 o1 = {y_re[2], y_im[2], y_re[3], y_im[3]};
    out4[ob + t * (2 * AN)]     = o0;
    out4[ob + t * (2 * AN) + 1] = o1;
  }
}

extern "C" void kernel_launch(void* const* d_in, const int* in_sizes, int n_in,
                              void* d_out, int out_size, void* d_ws, size_t ws_size,
                              hipStream_t stream) {
  const float* A_re  = (const float*)d_in[0];
  const float* A_im  = (const float*)d_in[1];
  const f32x4* X_re4 = (const f32x4*)d_in[2];
  const f32x4* X_im4 = (const f32x4*)d_in[3];
  f32x4* out4 = (f32x4*)d_out;
  (void)d_ws; (void)ws_size;

  const int blocks = BB * (AN / N4PB);   // 256 blocks

  // One-time: allow 153.6 KB dynamic LDS for pscan_v10 (MI355X has 160 KB).
  static int v10_ok = -1;
  if (v10_ok < 0) {
    hipError_t e = hipFuncSetAttribute(
        reinterpret_cast<const void*>(pscan_v10),
        hipFuncAttributeMaxDynamicSharedMemorySize, (int)SHMEM_BYTES);
    v10_ok = (e == hipSuccess) ? 1 : 0;
  }

  if (v10_ok) {
    pscan_v10<<<blocks, TPB, SHMEM_BYTES, stream>>>(A_re, A_im, X_re4, X_im4, out4);
  } else {
    pscan_onepass3<<<blocks, TPB, 0, stream>>>(A_re, A_im, X_re4, X_im4, out4);
  }
}